// Round 3
// baseline (316.313 us; speedup 1.0000x reference)
//
#include <hip/hip_runtime.h>
#include <hip/hip_cooperative_groups.h>

namespace cg = cooperative_groups;

// LELoss: scalar loss =
//   mean_B sum_D (x - decoded)^2
// + 1.1 * mean_B sum_E (encoded - latent @ rsrA^T)^2
// + 0.1 * mean_{20x20} (rsrA^T rsrA - I)^2
//
// R4: single cooperative kernel. R2/R3 showed main is latency/BW-bound, not
// instruction-bound (removing the LDS round-trip was neutral). The remaining
// controllable cost is the second kernel: its ~2us launch, ~2us exec, and the
// full-GPU drain between main and final. Fuse via grid.sync():
//   GRID=1024 x BLK=256, __launch_bounds__(256,4) -> VGPR<=128, 4 blk/CU,
//   exactly co-resident on 256 CUs. Each thread: 8 float4 A-pairs (2 batches),
//   4 B-elements (same rsrA row e=gid&127 for all 4 since NT%128==0).
//   Part B's 80 FMAs hide A-batch-2's load latency. Gram in block 0 only.
// After block partials: __threadfence + grid.sync, block 0 reduces 1024
// partials (one float4/thread) and writes out[0].

#define BB 8192
#define DD 1024
#define EE 128
#define EEP 129                 // sAT leading-dim pad (Gram term, block 0 only)
#define II 20
#define GRID 1024
#define BLK 256
#define NT (GRID * BLK)         // 262144 threads

// Fallback (cooperative launch unavailable): R3's two-kernel path.
#define GRID2 2048
#define GSZ2 (GRID2 * BLK)

// Force a wave-uniform pointer into SGPRs so constant-offset loads become
// s_load (scalar path) instead of 64 redundant per-lane VMEM loads.
__device__ __forceinline__ const float* uniform_ptr(const float* p) {
    unsigned long long v = (unsigned long long)p;
    unsigned lo = __builtin_amdgcn_readfirstlane((unsigned)v);
    unsigned hi = __builtin_amdgcn_readfirstlane((unsigned)(v >> 32));
    return (const float*)(((unsigned long long)hi << 32) | lo);
}

__device__ __forceinline__ float dot20(const float4& t0, const float4& t1,
                                       const float4& t2, const float4& t3,
                                       const float4& t4,
                                       const float* __restrict__ l) {
    float z;
    z = t0.x * l[0];
    z = fmaf(t0.y, l[1], z);
    z = fmaf(t0.z, l[2], z);
    z = fmaf(t0.w, l[3], z);
    z = fmaf(t1.x, l[4], z);
    z = fmaf(t1.y, l[5], z);
    z = fmaf(t1.z, l[6], z);
    z = fmaf(t1.w, l[7], z);
    z = fmaf(t2.x, l[8], z);
    z = fmaf(t2.y, l[9], z);
    z = fmaf(t2.z, l[10], z);
    z = fmaf(t2.w, l[11], z);
    z = fmaf(t3.x, l[12], z);
    z = fmaf(t3.y, l[13], z);
    z = fmaf(t3.z, l[14], z);
    z = fmaf(t3.w, l[15], z);
    z = fmaf(t4.x, l[16], z);
    z = fmaf(t4.y, l[17], z);
    z = fmaf(t4.z, l[18], z);
    z = fmaf(t4.w, l[19], z);
    return z;
}

#define ACC8(A, B)                                  \
    do {                                            \
        float d_;                                   \
        d_ = (A).x - (B).x; accA = fmaf(d_, d_, accA); \
        d_ = (A).y - (B).y; accA = fmaf(d_, d_, accA); \
        d_ = (A).z - (B).z; accA = fmaf(d_, d_, accA); \
        d_ = (A).w - (B).w; accA = fmaf(d_, d_, accA); \
    } while (0)

__global__ __launch_bounds__(BLK, 4) void leloss_fused(
    const float* __restrict__ x,
    const float* __restrict__ encoded,
    const float* __restrict__ latent,
    const float* __restrict__ decoded,
    const float* __restrict__ rsrA,
    float* __restrict__ partials,
    float* __restrict__ out)
{
    __shared__ float sAT[II * EEP];   // Gram staging, used by block 0 only
    __shared__ float sred[4];

    const int tid = threadIdx.x;
    const int gid = blockIdx.x * BLK + tid;

    const float4* __restrict__ x4 = (const float4*)x;
    const float4* __restrict__ d4 = (const float4*)decoded;

    // ---- A batch 1: 4 float4 pairs in flight ----
    float4 a0 = x4[gid];
    float4 b0 = d4[gid];
    float4 a1 = x4[gid + NT];
    float4 b1 = d4[gid + NT];
    float4 a2 = x4[gid + 2 * NT];
    float4 b2 = d4[gid + 2 * NT];
    float4 a3 = x4[gid + 3 * NT];
    float4 b3 = d4[gid + 3 * NT];

    // ---- B loads: 4 encoded elems + per-lane rsrA row (NT%128==0 -> same e) ----
    const float enc0 = encoded[gid];
    const float enc1 = encoded[gid + NT];
    const float enc2 = encoded[gid + 2 * NT];
    const float enc3 = encoded[gid + 3 * NT];

    const int e = gid & (EE - 1);
    const float4* __restrict__ r4 = (const float4*)(rsrA + e * II);
    float4 t0 = r4[0];
    float4 t1 = r4[1];
    float4 t2 = r4[2];
    float4 t3 = r4[3];
    float4 t4 = r4[4];

    // ---- Gram term: block 0 only; hides under block 0's own load waits ----
    float accC = 0.f;
    if (blockIdx.x == 0) {
        for (int t = tid; t < EE * II; t += BLK) {
            int ee = t / II, k = t - ee * II;
            sAT[k * EEP + ee] = rsrA[t];
        }
        __syncthreads();
        for (int t = tid; t < II * II; t += BLK) {
            const int i2 = t / II, j2 = t - i2 * II;
            float g = 0.f;
#pragma unroll 8
            for (int eidx = 0; eidx < EE; ++eidx)
                g = fmaf(sAT[i2 * EEP + eidx], sAT[j2 * EEP + eidx], g);
            if (i2 == j2) g -= 1.f;
            accC = fmaf(g, g, accC);
        }
    }

    // ---- consume A batch 1 ----
    float accA = 0.f;
    ACC8(a0, b0);
    ACC8(a1, b1);
    ACC8(a2, b2);
    ACC8(a3, b3);

    // ---- issue A batch 2 (reuse regs); B compute hides its latency ----
    a0 = x4[gid + 4 * NT];
    b0 = d4[gid + 4 * NT];
    a1 = x4[gid + 5 * NT];
    b1 = d4[gid + 5 * NT];
    a2 = x4[gid + 6 * NT];
    b2 = d4[gid + 6 * NT];
    a3 = x4[gid + 7 * NT];
    b3 = d4[gid + 7 * NT];

    // ---- Part B: 4 (b,e) elements; brow uniform per wave -> s_load latent ----
    float accB = 0.f;
    {
        const int brow0 = gid >> 7;   // + k*2048 per element
        const float* __restrict__ l0 = uniform_ptr(latent + brow0 * II);
        const float* __restrict__ l1 = uniform_ptr(latent + (brow0 + 2048) * II);
        const float* __restrict__ l2 = uniform_ptr(latent + (brow0 + 4096) * II);
        const float* __restrict__ l3 = uniform_ptr(latent + (brow0 + 6144) * II);
        float f;
        f = enc0 - dot20(t0, t1, t2, t3, t4, l0); accB = fmaf(f, f, accB);
        f = enc1 - dot20(t0, t1, t2, t3, t4, l1); accB = fmaf(f, f, accB);
        f = enc2 - dot20(t0, t1, t2, t3, t4, l2); accB = fmaf(f, f, accB);
        f = enc3 - dot20(t0, t1, t2, t3, t4, l3); accB = fmaf(f, f, accB);
    }

    // ---- consume A batch 2 ----
    ACC8(a0, b0);
    ACC8(a1, b1);
    ACC8(a2, b2);
    ACC8(a3, b3);

    float total = accA * (1.0f / BB)
                + accB * (1.1f / BB)
                + accC * (0.1f / (II * II));

    // ---- block reduce ----
#pragma unroll
    for (int off = 32; off > 0; off >>= 1)
        total += __shfl_down(total, off, 64);
    if ((tid & 63) == 0) sred[tid >> 6] = total;
    __syncthreads();
    if (tid == 0)
        partials[blockIdx.x] = sred[0] + sred[1] + sred[2] + sred[3];

    // ---- grid-wide barrier, then block 0 does the final 1024-float reduce ----
    __threadfence();                    // release partials to device scope
    cg::this_grid().sync();

    if (blockIdx.x == 0) {
        const float4* __restrict__ p4 = (const float4*)partials;
        float4 v = p4[tid];             // 256 threads x float4 = 1024 floats
        float acc = (v.x + v.y) + (v.z + v.w);
#pragma unroll
        for (int off = 32; off > 0; off >>= 1)
            acc += __shfl_down(acc, off, 64);
        if ((tid & 63) == 0) sred[tid >> 6] = acc;
        __syncthreads();
        if (tid == 0) out[0] = sred[0] + sred[1] + sred[2] + sred[3];
    }
}

// ---------------- fallback: R3's two-kernel path ----------------

__global__ __launch_bounds__(BLK) void leloss_main2(
    const float* __restrict__ x,
    const float* __restrict__ encoded,
    const float* __restrict__ latent,
    const float* __restrict__ decoded,
    const float* __restrict__ rsrA,
    float* __restrict__ partials)
{
    __shared__ float sAT[II * EEP];
    __shared__ float sred[4];

    const int tid = threadIdx.x;
    const int gid = blockIdx.x * BLK + tid;

    const float4* __restrict__ x4 = (const float4*)x;
    const float4* __restrict__ d4 = (const float4*)decoded;
    float4 a0 = x4[gid];
    float4 b0 = d4[gid];
    float4 a1 = x4[gid + GSZ2];
    float4 b1 = d4[gid + GSZ2];
    float4 a2 = x4[gid + 2 * GSZ2];
    float4 b2 = d4[gid + 2 * GSZ2];
    float4 a3 = x4[gid + 3 * GSZ2];
    float4 b3 = d4[gid + 3 * GSZ2];

    const float enc0 = encoded[gid];
    const float enc1 = encoded[gid + GSZ2];

    const int e = gid & (EE - 1);
    const float4* __restrict__ r4 = (const float4*)(rsrA + e * II);
    float4 t0 = r4[0];
    float4 t1 = r4[1];
    float4 t2 = r4[2];
    float4 t3 = r4[3];
    float4 t4 = r4[4];

    float accC = 0.f;
    if (blockIdx.x == 0) {
        for (int t = tid; t < EE * II; t += BLK) {
            int ee = t / II, k = t - ee * II;
            sAT[k * EEP + ee] = rsrA[t];
        }
        __syncthreads();
        for (int t = tid; t < II * II; t += BLK) {
            const int i2 = t / II, j2 = t - i2 * II;
            float g = 0.f;
#pragma unroll 8
            for (int eidx = 0; eidx < EE; ++eidx)
                g = fmaf(sAT[i2 * EEP + eidx], sAT[j2 * EEP + eidx], g);
            if (i2 == j2) g -= 1.f;
            accC = fmaf(g, g, accC);
        }
    }

    float accA = 0.f;
    ACC8(a0, b0);
    ACC8(a1, b1);
    ACC8(a2, b2);
    ACC8(a3, b3);

    float accB = 0.f;
    {
        const int brow = gid >> 7;
        const float* __restrict__ l0 = uniform_ptr(latent + brow * II);
        const float* __restrict__ l1 = uniform_ptr(latent + (brow + (GSZ2 >> 7)) * II);
        float f0 = enc0 - dot20(t0, t1, t2, t3, t4, l0);
        float f1 = enc1 - dot20(t0, t1, t2, t3, t4, l1);
        accB = fmaf(f0, f0, f1 * f1);
    }

    float total = accA * (1.0f / BB)
                + accB * (1.1f / BB)
                + accC * (0.1f / (II * II));

#pragma unroll
    for (int off = 32; off > 0; off >>= 1)
        total += __shfl_down(total, off, 64);
    if ((tid & 63) == 0) sred[tid >> 6] = total;
    __syncthreads();
    if (tid == 0)
        partials[blockIdx.x] = sred[0] + sred[1] + sred[2] + sred[3];
}

__global__ __launch_bounds__(BLK) void leloss_final2(
    const float* __restrict__ partials,
    float* __restrict__ out)
{
    __shared__ float sred[4];
    const int tid = threadIdx.x;

    const float4* __restrict__ p4 = (const float4*)partials;
    float4 v0 = p4[tid];
    float4 v1 = p4[tid + BLK];
    float acc = ((v0.x + v0.y) + (v0.z + v0.w))
              + ((v1.x + v1.y) + (v1.z + v1.w));

#pragma unroll
    for (int off = 32; off > 0; off >>= 1)
        acc += __shfl_down(acc, off, 64);
    if ((tid & 63) == 0) sred[tid >> 6] = acc;
    __syncthreads();
    if (tid == 0) out[0] = sred[0] + sred[1] + sred[2] + sred[3];
}

extern "C" void kernel_launch(void* const* d_in, const int* in_sizes, int n_in,
                              void* d_out, int out_size, void* d_ws, size_t ws_size,
                              hipStream_t stream) {
    const float* x       = (const float*)d_in[0];
    const float* encoded = (const float*)d_in[1];
    const float* latent  = (const float*)d_in[2];
    const float* decoded = (const float*)d_in[3];
    const float* rsrA    = (const float*)d_in[4];
    float* out      = (float*)d_out;
    float* partials = (float*)d_ws;   // 1024 floats; every slot written before read

    void* args[] = {(void*)&x, (void*)&encoded, (void*)&latent, (void*)&decoded,
                    (void*)&rsrA, (void*)&partials, (void*)&out};
    hipError_t err = hipLaunchCooperativeKernel((const void*)leloss_fused,
                                                dim3(GRID), dim3(BLK),
                                                args, 0, stream);
    if (err != hipSuccess) {
        // Fallback: two-kernel path (R3 shape).
        leloss_main2<<<GRID2, BLK, 0, stream>>>(x, encoded, latent, decoded, rsrA, partials);
        leloss_final2<<<1, BLK, 0, stream>>>(partials, out);
    }
}

// Round 4
// 106.027 us; speedup vs baseline: 2.9833x; 2.9833x over previous
//
#include <hip/hip_runtime.h>

// LELoss: scalar loss =
//   mean_B sum_D (x - decoded)^2
// + 1.1 * mean_B sum_E (encoded - latent @ rsrA^T)^2   (lambda1 + duplicated 0.1 term;
//                                                       kNN top-k is dead code)
// + 0.1 * mean_{20x20} (rsrA^T rsrA - I)^2
//
// Shapes fixed: x,decoded [8192,1024] f32; encoded [8192,128]; latent [8192,20];
// rsrA [128,20]. Output: 1 float.
//
// R5 = revert to R1 (best measured: 106.0us). Session evidence:
//  - R2/R3: stripping ~60 inst/thread from main's critical path = neutral
//    -> main is BW/latency-bound at ~14-16us vs 11.3us floor (72MB @ 6.6TB/s).
//  - R4: cooperative grid.sync fusion = 220us kernel (VALUBusy 0.8%, HBM 2%):
//    device-scope spin across 8 non-coherent XCD L2s. Same family as R1's
//    measured ~15us same-address atomic tail. Convergence primitives are
//    off-limits on this chip at this grid size.
//  - Timed window = 2x 256MiB harness ws-poison fills (82.6us, invariant)
//    + main + final + graph gaps. Controllable headroom ~5us with no live lever.
//
// Structure: K1 (2048 blocks) computes parts A+B everywhere and folds the tiny
// Gram term into block 0's partial (its ~3us of VALU/LDS work hides inside
// block 0's own global-load stalls). K2 (1 block) only sums the 2048 partials.
// No atomics, no memset nodes.

#define BB 8192
#define DD 1024
#define EE 128
#define EEP 129                 // sAT leading-dim pad: breaks stride-128 bank aliasing
#define II 20
#define GRID 2048
#define BLK 256
#define GSZ (GRID * BLK)        // 524288 threads; A: 4 float4-pairs/thread, B: 2 elems/thread

// Force a wave-uniform pointer into SGPRs so constant-offset loads become
// s_load (scalar path) instead of 64 redundant per-lane VMEM loads.
__device__ __forceinline__ const float* uniform_ptr(const float* p) {
    unsigned long long v = (unsigned long long)p;
    unsigned lo = __builtin_amdgcn_readfirstlane((unsigned)v);
    unsigned hi = __builtin_amdgcn_readfirstlane((unsigned)(v >> 32));
    return (const float*)(((unsigned long long)hi << 32) | lo);
}

__global__ __launch_bounds__(BLK) void leloss_main(
    const float* __restrict__ x,
    const float* __restrict__ encoded,
    const float* __restrict__ latent,
    const float* __restrict__ decoded,
    const float* __restrict__ rsrA,
    float* __restrict__ partials)
{
    // rsrA transposed in LDS: sAT[k*EEP + e] = rsrA[e*II + k]
    // Part B: lanes vary e -> consecutive banks (conflict-free).
    // Gram:   lanes vary i2, fixed e -> bank (i2*129+e)%32 varies with i2 (conflict-free).
    __shared__ float sAT[II * EEP];
    __shared__ float sred[4];

    const int tid = threadIdx.x;
    const int gid = blockIdx.x * BLK + tid;

    // ---- Part A loads: 4 independent float4 pairs, all in flight at once ----
    const float4* __restrict__ x4 = (const float4*)x;
    const float4* __restrict__ d4 = (const float4*)decoded;
    float4 a0 = x4[gid];
    float4 b0 = d4[gid];
    float4 a1 = x4[gid + GSZ];
    float4 b1 = d4[gid + GSZ];
    float4 a2 = x4[gid + 2 * GSZ];
    float4 b2 = d4[gid + 2 * GSZ];
    float4 a3 = x4[gid + 3 * GSZ];
    float4 b3 = d4[gid + 3 * GSZ];

    // ---- Part B loads: coalesced, issued early ----
    const float enc0 = encoded[gid];
    const float enc1 = encoded[gid + GSZ];

    // ---- stage rsrA^T into LDS while global loads are in flight ----
    for (int t = tid; t < EE * II; t += BLK) {
        int e = t / II, k = t - e * II;
        sAT[k * EEP + e] = rsrA[t];
    }
    __syncthreads();

    // ---- Gram term: block 0 only; overlaps block 0's global-load latency ----
    float accC = 0.f;
    if (blockIdx.x == 0) {
        for (int t = tid; t < II * II; t += BLK) {
            const int i2 = t / II, j2 = t - i2 * II;
            float g = 0.f;
#pragma unroll 8
            for (int e = 0; e < EE; ++e)
                g = fmaf(sAT[i2 * EEP + e], sAT[j2 * EEP + e], g);
            if (i2 == j2) g -= 1.f;
            accC = fmaf(g, g, accC);
        }
    }

    // ---- Part A compute ----
    float accA = 0.f;
    {
        float d;
        d = a0.x - b0.x; accA = fmaf(d, d, accA);
        d = a0.y - b0.y; accA = fmaf(d, d, accA);
        d = a0.z - b0.z; accA = fmaf(d, d, accA);
        d = a0.w - b0.w; accA = fmaf(d, d, accA);
        d = a1.x - b1.x; accA = fmaf(d, d, accA);
        d = a1.y - b1.y; accA = fmaf(d, d, accA);
        d = a1.z - b1.z; accA = fmaf(d, d, accA);
        d = a1.w - b1.w; accA = fmaf(d, d, accA);
        d = a2.x - b2.x; accA = fmaf(d, d, accA);
        d = a2.y - b2.y; accA = fmaf(d, d, accA);
        d = a2.z - b2.z; accA = fmaf(d, d, accA);
        d = a2.w - b2.w; accA = fmaf(d, d, accA);
        d = a3.x - b3.x; accA = fmaf(d, d, accA);
        d = a3.y - b3.y; accA = fmaf(d, d, accA);
        d = a3.z - b3.z; accA = fmaf(d, d, accA);
        d = a3.w - b3.w; accA = fmaf(d, d, accA);
    }

    // ---- Part B: two (b,e) elements per thread; b row wave-uniform ----
    float accB = 0.f;
    {
        const int e = gid & (EE - 1);
        const int brow = gid >> 7;   // uniform per wave (wave spans half of E=128)
        const float* __restrict__ l0 = uniform_ptr(latent + brow * II);
        const float* __restrict__ l1 = uniform_ptr(latent + (brow + (GSZ >> 7)) * II);
        float z0 = 0.f, z1 = 0.f;
#pragma unroll
        for (int k = 0; k < II; ++k) {
            const float w = sAT[k * EEP + e];  // consecutive banks across lanes
            z0 = fmaf(l0[k], w, z0);           // s_load scalar reads
            z1 = fmaf(l1[k], w, z1);
        }
        const float f0 = enc0 - z0;
        const float f1 = enc1 - z1;
        accB = fmaf(f0, f0, fmaf(f1, f1, 0.f));
    }

    float total = accA * (1.0f / BB)
                + accB * (1.1f / BB)
                + accC * (0.1f / (II * II));

    // ---- block reduce: wave64 shuffle, 4 waves via LDS, plain store ----
#pragma unroll
    for (int off = 32; off > 0; off >>= 1)
        total += __shfl_down(total, off, 64);
    if ((tid & 63) == 0) sred[tid >> 6] = total;
    __syncthreads();
    if (tid == 0)
        partials[blockIdx.x] = sred[0] + sred[1] + sred[2] + sred[3];
}

__global__ __launch_bounds__(BLK) void leloss_final(
    const float* __restrict__ partials,
    float* __restrict__ out)
{
    __shared__ float sred[4];
    const int tid = threadIdx.x;

    float acc = 0.f;
#pragma unroll
    for (int j = 0; j < GRID / BLK; ++j)
        acc += partials[j * BLK + tid];

#pragma unroll
    for (int off = 32; off > 0; off >>= 1)
        acc += __shfl_down(acc, off, 64);
    if ((tid & 63) == 0) sred[tid >> 6] = acc;
    __syncthreads();
    if (tid == 0) out[0] = sred[0] + sred[1] + sred[2] + sred[3];
}

extern "C" void kernel_launch(void* const* d_in, const int* in_sizes, int n_in,
                              void* d_out, int out_size, void* d_ws, size_t ws_size,
                              hipStream_t stream) {
    const float* x       = (const float*)d_in[0];
    const float* encoded = (const float*)d_in[1];
    const float* latent  = (const float*)d_in[2];
    const float* decoded = (const float*)d_in[3];
    const float* rsrA    = (const float*)d_in[4];
    float* out      = (float*)d_out;
    float* partials = (float*)d_ws;   // 2048 floats; every slot written by K1

    leloss_main<<<GRID, BLK, 0, stream>>>(x, encoded, latent, decoded, rsrA, partials);
    leloss_final<<<1, BLK, 0, stream>>>(partials, out);
}